// Round 1
// baseline (349.108 us; speedup 1.0000x reference)
//
#include <hip/hip_runtime.h>
#include <hip/hip_bf16.h>
#include <cstdint>
#include <cstddef>

#define Z 256
#define BT 128
#define BK 64

typedef __attribute__((ext_vector_type(8))) short short8_t;
typedef __attribute__((ext_vector_type(4))) float f32x4;

#define GLOAD_LDS16(g, l)                                                              \
  __builtin_amdgcn_global_load_lds((const __attribute__((address_space(1))) void*)(g), \
                                   (__attribute__((address_space(3))) void*)(l), 16, 0, 0)

__device__ __forceinline__ unsigned short f2bf(float x) {
  __hip_bfloat16 h = __float2bfloat16(x);
  return *reinterpret_cast<unsigned short*>(&h);
}

// fp32 -> bf16 cast + row sum-of-squares. One wave per row (4 rows / 256-thr block).
__global__ __launch_bounds__(256) void prep_kernel(const float* __restrict__ src,
                                                   unsigned short* __restrict__ dst,
                                                   float* __restrict__ sq, int nrows) {
  int row = blockIdx.x * 4 + (threadIdx.x >> 6);
  int lane = threadIdx.x & 63;
  if (row >= nrows) return;
  const float4 v = *reinterpret_cast<const float4*>(src + (size_t)row * Z + lane * 4);
  float s = v.x * v.x + v.y * v.y + v.z * v.z + v.w * v.w;
#pragma unroll
  for (int m = 32; m >= 1; m >>= 1) s += __shfl_xor(s, m);
  if (lane == 0) sq[row] = s;
  ushort4 o;
  o.x = f2bf(v.x); o.y = f2bf(v.y); o.z = f2bf(v.z); o.w = f2bf(v.w);
  *reinterpret_cast<ushort4*>(dst + (size_t)row * Z + lane * 4) = o;
}

// Fused bf16 GEMM (C = mean . e^T) + logits + per-column partial logsumexp.
// 128x128 tile, BK=64, 4 waves (2x2), double-buffered global_load_lds staging,
// XOR-swizzled LDS (16B-slot ^ (row&7)) to kill the 16-way ds_read_b128 conflict.
__global__ __launch_bounds__(256, 2) void gemm_lse_kernel(
    const unsigned short* __restrict__ Abf,  // [N][Z] bf16 bits
    const unsigned short* __restrict__ Bbf,  // [M][Z]
    const float* __restrict__ a2, const float* __restrict__ b2,
    const int* __restrict__ sigma_p,
    float2* __restrict__ part,  // [N/BT][M] (max, sumexp)
    int Mtot) {
  __shared__ __align__(16) unsigned short As[2][BT * BK];
  __shared__ __align__(16) unsigned short Bs[2][BT * BK];
  __shared__ float a2s[BT], b2s[BT];
  __shared__ float redM[2][BT], redS[2][BT];

  const int tid = threadIdx.x;
  const int lane = tid & 63;
  const int w = tid >> 6;
  const int wn = w >> 1, wm = w & 1;
  const int laneLo = lane & 15, laneHi = lane >> 4;

  const int mb = blockIdx.x, nb = blockIdx.y;
  const int row0 = nb * BT, col0 = mb * BT;

  auto stage = [&](int buf, int k0) {
#pragma unroll
    for (int i = 0; i < 4; ++i) {
      int o = i * 4096 + tid * 16;              // byte offset within 16 KB tile
      int r = o >> 7;                           // 128 B per LDS row (64 bf16)
      int sg = ((o >> 4) & 7) ^ (r & 7);        // source 16B-slot (inverse swizzle)
      GLOAD_LDS16(Abf + (size_t)(row0 + r) * Z + k0 + sg * 8,
                  (char*)(&As[buf][0]) + o);
    }
#pragma unroll
    for (int i = 0; i < 4; ++i) {
      int o = i * 4096 + tid * 16;
      int r = o >> 7;
      int sg = ((o >> 4) & 7) ^ (r & 7);
      GLOAD_LDS16(Bbf + (size_t)(col0 + r) * Z + k0 + sg * 8,
                  (char*)(&Bs[buf][0]) + o);
    }
  };

  stage(0, 0);
  if (tid < BT) a2s[tid] = a2[row0 + tid];
  else          b2s[tid - BT] = b2[col0 + tid - BT];

  f32x4 acc[4][4];
#pragma unroll
  for (int a = 0; a < 4; ++a)
#pragma unroll
    for (int b = 0; b < 4; ++b) acc[a][b] = f32x4{0.f, 0.f, 0.f, 0.f};

  __syncthreads();

  const int NT = Z / BK;  // 4 k-steps
#pragma unroll
  for (int t = 0; t < NT; ++t) {
    if (t + 1 < NT) stage((t + 1) & 1, (t + 1) * BK);
    const unsigned short* Ab = &As[t & 1][0];
    const unsigned short* Bb = &Bs[t & 1][0];
#pragma unroll
    for (int kk = 0; kk < 2; ++kk) {
      short8_t af[4], bfv[4];
      const int cb = kk * 64 + laneHi * 16;  // logical byte-col of this lane's 16B
#pragma unroll
      for (int f = 0; f < 4; ++f) {
        int ra = wn * 64 + f * 16 + laneLo;
        af[f] = *reinterpret_cast<const short8_t*>(
            reinterpret_cast<const char*>(Ab) + ra * 128 + (cb ^ ((ra & 7) << 4)));
        int rb = wm * 64 + f * 16 + laneLo;
        bfv[f] = *reinterpret_cast<const short8_t*>(
            reinterpret_cast<const char*>(Bb) + rb * 128 + (cb ^ ((rb & 7) << 4)));
      }
#pragma unroll
      for (int a = 0; a < 4; ++a)
#pragma unroll
        for (int b = 0; b < 4; ++b)
          acc[a][b] = __builtin_amdgcn_mfma_f32_16x16x32_bf16(af[a], bfv[b], acc[a][b], 0, 0, 0);
    }
    __syncthreads();
  }

  // epilogue: logits = (2*ab - a2 - b2) * inv2s2; per-column max & sumexp over 128 rows
  const float sgm = (float)(*sigma_p);
  const float inv2s2 = 1.f / (2.f * sgm * sgm);
  const float c1 = 2.f * inv2s2;

  float a2v[4][4];
#pragma unroll
  for (int a = 0; a < 4; ++a)
#pragma unroll
    for (int j = 0; j < 4; ++j)
      a2v[a][j] = a2s[wn * 64 + a * 16 + laneHi * 4 + j];

#pragma unroll
  for (int b = 0; b < 4; ++b) {
    float b2m = b2s[wm * 64 + b * 16 + laneLo];
    float tv[16];
    float mx = -INFINITY;
#pragma unroll
    for (int a = 0; a < 4; ++a)
#pragma unroll
      for (int j = 0; j < 4; ++j) {
        float v = c1 * acc[a][b][j] - inv2s2 * (a2v[a][j] + b2m);
        tv[a * 4 + j] = v;
        mx = fmaxf(mx, v);
      }
    mx = fmaxf(mx, __shfl_xor(mx, 16));
    mx = fmaxf(mx, __shfl_xor(mx, 32));
    float ssum = 0.f;
#pragma unroll
    for (int i = 0; i < 16; ++i) ssum += __expf(tv[i] - mx);
    ssum += __shfl_xor(ssum, 16);
    ssum += __shfl_xor(ssum, 32);
    if (laneHi == 0) {
      redM[wn][wm * 64 + b * 16 + laneLo] = mx;
      redS[wn][wm * 64 + b * 16 + laneLo] = ssum;
    }
  }
  __syncthreads();
  if (tid < BT) {
    float m0 = redM[0][tid], m1 = redM[1][tid];
    float s0 = redS[0][tid], s1 = redS[1][tid];
    float Mx = fmaxf(m0, m1);
    float Sx = s0 * __expf(m0 - Mx) + s1 * __expf(m1 - Mx);
    part[(size_t)nb * Mtot + col0 + tid] = make_float2(Mx, Sx);
  }
}

// Merge NB partials per column -> lse; block-reduce; atomicAdd(-lse/M) into out.
__global__ __launch_bounds__(256) void lse_finish(const float2* __restrict__ part,
                                                  int NB, int Mtot,
                                                  float* __restrict__ out) {
  int m = blockIdx.x * blockDim.x + threadIdx.x;
  float mx = -INFINITY, s = 0.f;
  for (int b = 0; b < NB; ++b) {
    float2 p = part[(size_t)b * Mtot + m];
    float nm = fmaxf(mx, p.x);
    s = s * __expf(mx - nm) + p.y * __expf(p.x - nm);
    mx = nm;
  }
  float lse = mx + __logf(s);
  float v = lse;
#pragma unroll
  for (int off = 32; off >= 1; off >>= 1) v += __shfl_xor(v, off);
  __shared__ float red[4];
  if ((threadIdx.x & 63) == 0) red[threadIdx.x >> 6] = v;
  __syncthreads();
  if (threadIdx.x == 0)
    atomicAdd(out, -(red[0] + red[1] + red[2] + red[3]) / (float)Mtot);
}

extern "C" void kernel_launch(void* const* d_in, const int* in_sizes, int n_in,
                              void* d_out, int out_size, void* d_ws, size_t ws_size,
                              hipStream_t stream) {
  const float* mean = (const float*)d_in[0];
  const float* e    = (const float*)d_in[1];
  const int* sigma  = (const int*)d_in[2];
  const int N_ = in_sizes[0] / Z;  // 32768
  const int M_ = in_sizes[1] / Z;  // 8192
  const int NB = N_ / BT;          // 256

  char* ws = (char*)d_ws;
  unsigned short* Abf = (unsigned short*)ws; ws += (size_t)N_ * Z * sizeof(unsigned short);
  unsigned short* Bbf = (unsigned short*)ws; ws += (size_t)M_ * Z * sizeof(unsigned short);
  float* a2 = (float*)ws;                    ws += (size_t)N_ * sizeof(float);
  float* b2 = (float*)ws;                    ws += (size_t)M_ * sizeof(float);
  float2* part = (float2*)ws;                // NB * M_ float2 = 16 MB

  hipMemsetAsync(d_out, 0, sizeof(float), stream);
  prep_kernel<<<N_ / 4, 256, 0, stream>>>(mean, Abf, a2, N_);
  prep_kernel<<<M_ / 4, 256, 0, stream>>>(e, Bbf, b2, M_);
  dim3 grid(M_ / BT, N_ / BT);
  gemm_lse_kernel<<<grid, 256, 0, stream>>>(Abf, Bbf, a2, b2, sigma, part, M_);
  lse_finish<<<M_ / 256, 256, 0, stream>>>(part, NB, M_, (float*)d_out);
}

// Round 2
// 290.363 us; speedup vs baseline: 1.2023x; 1.2023x over previous
//
#include <hip/hip_runtime.h>
#include <hip/hip_bf16.h>
#include <cstdint>
#include <cstddef>

#define Z 256     // latent dim (K)
#define CG 64     // columns (e-rows) per block
#define RT 64     // mean-rows per tile
#define BK 128    // K elems per staged A piece
#define NCH 4     // N split into 4 chunks

typedef __attribute__((ext_vector_type(8))) short short8_t;
typedef __attribute__((ext_vector_type(4))) float f32x4;

#define GLOAD_LDS16(g, l)                                                              \
  __builtin_amdgcn_global_load_lds((const __attribute__((address_space(1))) void*)(g), \
                                   (__attribute__((address_space(3))) void*)(l), 16, 0, 0)

__device__ __forceinline__ unsigned short f2bf(float x) {
  __hip_bfloat16 h = __float2bfloat16(x);
  return *reinterpret_cast<unsigned short*>(&h);
}

// fp32 -> bf16 cast + row sum-of-squares. One wave per row.
__global__ __launch_bounds__(256) void prep_kernel(const float* __restrict__ src,
                                                   unsigned short* __restrict__ dst,
                                                   float* __restrict__ sq, int nrows) {
  int row = blockIdx.x * 4 + (threadIdx.x >> 6);
  int lane = threadIdx.x & 63;
  if (row >= nrows) return;
  const float4 v = *reinterpret_cast<const float4*>(src + (size_t)row * Z + lane * 4);
  float s = v.x * v.x + v.y * v.y + v.z * v.z + v.w * v.w;
#pragma unroll
  for (int m = 32; m >= 1; m >>= 1) s += __shfl_xor(s, m);
  if (lane == 0) sq[row] = s;
  ushort4 o;
  o.x = f2bf(v.x); o.y = f2bf(v.y); o.z = f2bf(v.z); o.w = f2bf(v.w);
  *reinterpret_cast<ushort4*>(dst + (size_t)row * Z + lane * 4) = o;
}

// stage one 64x128 A piece (16 KB) into S[BUF], XOR-swizzled
#define STAGE_A(BUF, T, KH)                                                             \
  {                                                                                     \
    _Pragma("unroll")                                                                   \
    for (int i = 0; i < 4; ++i) {                                                       \
      int o = i * 4096 + tid * 16;                                                      \
      int r = o >> 8;                                                                   \
      int sg = ((o >> 4) & 15) ^ (r & 7);                                               \
      GLOAD_LDS16(Abf + (size_t)(row0base + (T) * RT + r) * Z + (KH) * BK + sg * 8,     \
                  (char*)(&S[BUF][0]) + o);                                             \
    }                                                                                   \
  }

// 16 MFMA for one K-half piece; KH is a literal 0/1, BUF literal 0/1
#define COMPUTE_PIECE(BUF, KH)                                                          \
  {                                                                                     \
    const char* Ab = (const char*)(&S[BUF][0]);                                         \
    _Pragma("unroll")                                                                   \
    for (int kk = 0; kk < 4; ++kk) {                                                    \
      short8_t afr[2];                                                                  \
      const int cb = kk * 64 + laneHi * 16;                                             \
      _Pragma("unroll")                                                                 \
      for (int a = 0; a < 2; ++a) {                                                     \
        int ra = wr * 32 + a * 16 + laneLo;                                             \
        afr[a] = *reinterpret_cast<const short8_t*>(Ab + ra * 256 +                     \
                                                    (cb ^ ((ra & 7) << 4)));            \
      }                                                                                 \
      _Pragma("unroll")                                                                 \
      for (int a = 0; a < 2; ++a)                                                       \
        _Pragma("unroll")                                                               \
        for (int c = 0; c < 2; ++c)                                                     \
          acc[a][c] = __builtin_amdgcn_mfma_f32_16x16x32_bf16(                          \
              afr[a], bfr[c][(KH) * 4 + kk], acc[a][c], 0, 0, 0);                       \
    }                                                                                   \
  }

// Column-strip fused GEMM + online logsumexp over an 8192-row chunk.
// 4 waves (2 row-halves x 2 col-halves), B panel register-resident.
__global__ __launch_bounds__(256, 3) void gemm_lse_kernel(
    const unsigned short* __restrict__ Abf,  // [N][Z] bf16 bits
    const unsigned short* __restrict__ Bbf,  // [M][Z]
    const float* __restrict__ a2, const float* __restrict__ b2,
    const int* __restrict__ sigma_p,
    float2* __restrict__ part,  // [NCH][M]
    int Mtot, int chRows) {
  // 32 KB: B staging area (64x256) first, then A double-buffer 2x(64x128)
  __shared__ __align__(16) unsigned short S[2][RT * BK];
  __shared__ float redM[2][CG], redS[2][CG];

  const int tid = threadIdx.x;
  const int lane = tid & 63;
  const int w = tid >> 6;
  const int wr = w >> 1, wc = w & 1;
  const int laneLo = lane & 15, laneHi = lane >> 4;

  // XCD-affine mapping: 512 blocks, xcd = id&7 owns chunk y = xcd&3 -> its
  // 4 MB A-chunk stays L2-resident on that XCD.
  const int id = blockIdx.x;
  const int xcd = id & 7, sidx = id >> 3;
  const int y = xcd & 3;
  const int x = ((xcd >> 2) << 6) | sidx;

  const int row0base = y * chRows;
  const int col0 = x * CG;
  const int ntiles = chRows / RT;

  const float sgm = (float)(*sigma_p);
  const float inv2s2 = 1.f / (2.f * sgm * sgm);
  const float c1 = 2.f * inv2s2;

  // ---- stage B panel (64 cols x 256 K = 32 KB) into all of S, swizzled ----
#pragma unroll
  for (int i = 0; i < 8; ++i) {
    int o = i * 4096 + tid * 16;
    int r = o >> 9;
    int sg = ((o >> 4) & 31) ^ (r & 7);
    GLOAD_LDS16(Bbf + (size_t)(col0 + r) * Z + sg * 8, (char*)(&S[0][0]) + o);
  }
  __syncthreads();

  // ---- B panel -> registers (16 x short8 = 64 VGPR), statically indexed ----
  short8_t bfr[2][8];
  {
    const char* Bb = (const char*)(&S[0][0]);
#pragma unroll
    for (int c = 0; c < 2; ++c) {
      int rb = wc * 32 + c * 16 + laneLo;
#pragma unroll
      for (int kk = 0; kk < 8; ++kk) {
        int cb = kk * 64 + laneHi * 16;
        bfr[c][kk] = *reinterpret_cast<const short8_t*>(Bb + rb * 512 +
                                                        (cb ^ ((rb & 7) << 4)));
      }
    }
  }
  float b2i[2];
#pragma unroll
  for (int c = 0; c < 2; ++c)
    b2i[c] = b2[col0 + wc * 32 + c * 16 + laneLo] * inv2s2;
  __syncthreads();  // all waves done reading S before A staging overwrites

  f32x4 acc[2][2];
#pragma unroll
  for (int a = 0; a < 2; ++a)
#pragma unroll
    for (int c = 0; c < 2; ++c) acc[a][c] = f32x4{0.f, 0.f, 0.f, 0.f};
  float m_run[2] = {-1e30f, -1e30f};
  float s_run[2] = {0.f, 0.f};

  STAGE_A(0, 0, 0);
  __syncthreads();

  for (int t = 0; t < ntiles; ++t) {
    // even piece: K[0:128) from buf0; prefetch odd piece into buf1
    STAGE_A(1, t, 1);
    COMPUTE_PIECE(0, 0);
    __syncthreads();

    // odd piece: K[128:256) from buf1; prefetch next tile's even piece
    if (t + 1 < ntiles) STAGE_A(0, t + 1, 0);
    // a2 prefetch (L2-hit, hides under the 16 MFMAs below)
    const int rowt = row0base + t * RT + wr * 32;
    const float4 av0 = *reinterpret_cast<const float4*>(a2 + rowt + laneHi * 4);
    const float4 av1 = *reinterpret_cast<const float4*>(a2 + rowt + 16 + laneHi * 4);
    COMPUTE_PIECE(1, 1);

    // ---- epilogue: 16 logits/lane -> online (max, sumexp) per column ----
    float ai[2][4];
    ai[0][0] = av0.x * inv2s2; ai[0][1] = av0.y * inv2s2;
    ai[0][2] = av0.z * inv2s2; ai[0][3] = av0.w * inv2s2;
    ai[1][0] = av1.x * inv2s2; ai[1][1] = av1.y * inv2s2;
    ai[1][2] = av1.z * inv2s2; ai[1][3] = av1.w * inv2s2;
#pragma unroll
    for (int c = 0; c < 2; ++c) {
      float v[8];
#pragma unroll
      for (int a = 0; a < 2; ++a)
#pragma unroll
        for (int j = 0; j < 4; ++j)
          v[a * 4 + j] = c1 * acc[a][c][j] - (ai[a][j] + b2i[c]);
      float mx = fmaxf(fmaxf(fmaxf(v[0], v[1]), fmaxf(v[2], v[3])),
                       fmaxf(fmaxf(v[4], v[5]), fmaxf(v[6], v[7])));
      float nm = fmaxf(m_run[c], mx);
      float ssum = 0.f;
#pragma unroll
      for (int i = 0; i < 8; ++i) ssum += __expf(v[i] - nm);
      s_run[c] = s_run[c] * __expf(m_run[c] - nm) + ssum;
      m_run[c] = nm;
      acc[0][c] = f32x4{0.f, 0.f, 0.f, 0.f};
      acc[1][c] = f32x4{0.f, 0.f, 0.f, 0.f};
    }
    __syncthreads();
  }

  // ---- merge laneHi groups (shfl), then the two row-half waves (LDS) ----
#pragma unroll
  for (int c = 0; c < 2; ++c) {
#pragma unroll
    for (int off = 16; off <= 32; off <<= 1) {
      float om = __shfl_xor(m_run[c], off);
      float os = __shfl_xor(s_run[c], off);
      float nm = fmaxf(m_run[c], om);
      s_run[c] = s_run[c] * __expf(m_run[c] - nm) + os * __expf(om - nm);
      m_run[c] = nm;
    }
    if (laneHi == 0) {
      redM[wr][wc * 32 + c * 16 + laneLo] = m_run[c];
      redS[wr][wc * 32 + c * 16 + laneLo] = s_run[c];
    }
  }
  __syncthreads();
  if (tid < CG) {
    float m0 = redM[0][tid], m1 = redM[1][tid];
    float s0 = redS[0][tid], s1 = redS[1][tid];
    float Mx = fmaxf(m0, m1);
    float Sx = s0 * __expf(m0 - Mx) + s1 * __expf(m1 - Mx);
    part[(size_t)y * Mtot + col0 + tid] = make_float2(Mx, Sx);
  }
}

// Merge NCH partials per column -> lse; block-reduce; atomicAdd(-lse/M).
__global__ __launch_bounds__(256) void lse_finish(const float2* __restrict__ part,
                                                  int NB, int Mtot,
                                                  float* __restrict__ out) {
  int m = blockIdx.x * blockDim.x + threadIdx.x;
  float mx = -1e30f, s = 0.f;
  for (int b = 0; b < NB; ++b) {
    float2 p = part[(size_t)b * Mtot + m];
    float nm = fmaxf(mx, p.x);
    s = s * __expf(mx - nm) + p.y * __expf(p.x - nm);
    mx = nm;
  }
  float lse = mx + __logf(s);
  float v = lse;
#pragma unroll
  for (int off = 32; off >= 1; off >>= 1) v += __shfl_xor(v, off);
  __shared__ float red[4];
  if ((threadIdx.x & 63) == 0) red[threadIdx.x >> 6] = v;
  __syncthreads();
  if (threadIdx.x == 0)
    atomicAdd(out, -(red[0] + red[1] + red[2] + red[3]) / (float)Mtot);
}

extern "C" void kernel_launch(void* const* d_in, const int* in_sizes, int n_in,
                              void* d_out, int out_size, void* d_ws, size_t ws_size,
                              hipStream_t stream) {
  const float* mean = (const float*)d_in[0];
  const float* e    = (const float*)d_in[1];
  const int* sigma  = (const int*)d_in[2];
  const int N_ = in_sizes[0] / Z;  // 32768
  const int M_ = in_sizes[1] / Z;  // 8192
  const int chRows = N_ / NCH;     // 8192

  char* ws = (char*)d_ws;
  unsigned short* Abf = (unsigned short*)ws; ws += (size_t)N_ * Z * sizeof(unsigned short);
  unsigned short* Bbf = (unsigned short*)ws; ws += (size_t)M_ * Z * sizeof(unsigned short);
  float* a2 = (float*)ws;                    ws += (size_t)N_ * sizeof(float);
  float* b2 = (float*)ws;                    ws += (size_t)M_ * sizeof(float);
  float2* part = (float2*)ws;                // NCH * M_ float2 = 256 KB

  hipMemsetAsync(d_out, 0, sizeof(float), stream);
  prep_kernel<<<N_ / 4, 256, 0, stream>>>(mean, Abf, a2, N_);
  prep_kernel<<<M_ / 4, 256, 0, stream>>>(e, Bbf, b2, M_);
  gemm_lse_kernel<<<(M_ / CG) * NCH, 256, 0, stream>>>(Abf, Bbf, a2, b2, sigma,
                                                       part, M_, chRows);
  lse_finish<<<M_ / 256, 256, 0, stream>>>(part, NCH, M_, (float*)d_out);
}

// Round 3
// 223.624 us; speedup vs baseline: 1.5611x; 1.2984x over previous
//
#include <hip/hip_runtime.h>
#include <hip/hip_bf16.h>
#include <cstdint>
#include <cstddef>

#define Z 256      // latent dim (K)
#define CG 128     // e-columns per block
#define RT 64      // mean-rows per tile
#define NCH 8      // N chunks
#define LOG2E 1.4426950408889634f
#define LN2 0.6931471805599453f

typedef __attribute__((ext_vector_type(8))) short short8_t;
typedef __attribute__((ext_vector_type(4))) float f32x4;

#define GLOAD_LDS16(g, l)                                                              \
  __builtin_amdgcn_global_load_lds((const __attribute__((address_space(1))) void*)(g), \
                                   (__attribute__((address_space(3))) void*)(l), 16, 0, 0)

__device__ __forceinline__ unsigned short f2bf(float x) {
  __hip_bfloat16 h = __float2bfloat16(x);
  return *reinterpret_cast<unsigned short*>(&h);
}

__device__ __forceinline__ float fast_exp2(float x) {
#if __has_builtin(__builtin_amdgcn_exp2f)
  return __builtin_amdgcn_exp2f(x);
#else
  float r;
  asm("v_exp_f32 %0, %1" : "=v"(r) : "v"(x));
  return r;
#endif
}

// Combined prep: fp32->bf16 cast + row sum-of-squares for BOTH matrices.
// One 16-lane group per row (64B/lane), grid-stride.
__global__ __launch_bounds__(256) void prep_kernel(const float* __restrict__ mean,
                                                   const float* __restrict__ e,
                                                   unsigned short* __restrict__ dst,
                                                   float* __restrict__ sq,
                                                   int Nr, int Mr) {
  const int tid = threadIdx.x;
  const int lane16 = tid & 15;
  const int rgrp = tid >> 4;  // 16 rows per block-pass
  const int total = Nr + Mr;
  for (int base = blockIdx.x * 16; base < total; base += gridDim.x * 16) {
    const int row = base + rgrp;
    const float* src = (row < Nr) ? (mean + (size_t)row * Z)
                                  : (e + (size_t)(row - Nr) * Z);
    float4 v[4];
    float s = 0.f;
#pragma unroll
    for (int i = 0; i < 4; ++i) {
      v[i] = *reinterpret_cast<const float4*>(src + (lane16 + i * 16) * 4);
      s += v[i].x * v[i].x + v[i].y * v[i].y + v[i].z * v[i].z + v[i].w * v[i].w;
    }
    s += __shfl_xor(s, 1); s += __shfl_xor(s, 2);
    s += __shfl_xor(s, 4); s += __shfl_xor(s, 8);
    if (lane16 == 0) sq[row] = s;
    unsigned short* d = dst + (size_t)row * Z;
#pragma unroll
    for (int i = 0; i < 4; ++i) {
      ushort4 o;
      o.x = f2bf(v[i].x); o.y = f2bf(v[i].y);
      o.z = f2bf(v[i].z); o.w = f2bf(v[i].w);
      *reinterpret_cast<ushort4*>(d + (lane16 + i * 16) * 4) = o;
    }
  }
}

// stage one 64-row x 128-K A piece (16 KB) as [2][64][128B], XOR-swizzled source
#define STAGE_A(BUF, T, P)                                                            \
  {                                                                                   \
    _Pragma("unroll") for (int i = 0; i < 2; ++i) {                                   \
      int o = i * 8192 + tid * 16;                                                    \
      int h = o >> 13, r = (o >> 7) & 63, sg = ((o >> 4) & 7) ^ (r & 7);              \
      GLOAD_LDS16(Abf + (size_t)(row0base + (T) * RT + r) * Z + (P) * 128 +           \
                      h * 64 + sg * 8,                                                \
                  Sb + (BUF) * 16384 + o);                                            \
    }                                                                                 \
  }

// 16 MFMA for one 128-K piece (4 k32 steps x 2 row-frags x 2 col-frags)
#define COMPUTE(BUF, H)                                                               \
  {                                                                                   \
    _Pragma("unroll") for (int kk = 0; kk < 4; ++kk) {                                \
      short8_t afr[2];                                                                \
      const int cb = (kk & 1) * 64 + laneHi * 16;                                     \
      const int hh = kk >> 1;                                                         \
      _Pragma("unroll") for (int a = 0; a < 2; ++a) {                                 \
        int ra = wr * 32 + a * 16 + laneLo;                                           \
        afr[a] = *reinterpret_cast<const short8_t*>(                                  \
            Sb + (BUF) * 16384 + hh * 8192 + ra * 128 + (cb ^ ((ra & 7) << 4)));      \
      }                                                                               \
      _Pragma("unroll") for (int a = 0; a < 2; ++a)                                   \
          _Pragma("unroll") for (int c = 0; c < 2; ++c)                               \
              acc[a][c] = __builtin_amdgcn_mfma_f32_16x16x32_bf16(                    \
                  afr[a], bfr[c][(H) * 4 + kk], acc[a][c], 0, 0, 0);                  \
    }                                                                                 \
  }

// Column-strip fused GEMM + online logsumexp (exp2 domain).
// 8 waves (2 row x 4 col), B panel (32 cols/wave x K=256) register-resident.
__global__ __launch_bounds__(512, 4) void gemm_lse_kernel(
    const unsigned short* __restrict__ Abf,  // [N][Z] bf16 bits
    const unsigned short* __restrict__ Bbf,  // [M][Z]
    const float* __restrict__ a2, const float* __restrict__ b2,
    const int* __restrict__ sigma_p,
    float2* __restrict__ part,  // [NCH][M] (max2, sumexp2)
    int Mtot, int chRows) {
  __shared__ __align__(16) unsigned short S[16384];  // 32 KB, B-halves then A dbuf
  __shared__ float redM[2][CG], redS[2][CG];

  const int tid = threadIdx.x;
  const int lane = tid & 63;
  const int w = tid >> 6;             // 0..7
  const int wr = w >> 2, wc = w & 3;  // 2 row-halves x 4 col-quarters
  const int laneLo = lane & 15, laneHi = lane >> 4;
  char* Sb = (char*)&S[0];

  // XCD-affine: xcd = id&7 owns N-chunk y -> its 2 MB A-chunk stays L2-resident
  const int id = blockIdx.x;
  const int y = id & 7;
  const int x = id >> 3;
  const int row0base = y * chRows;
  const int col0 = x * CG;
  const int ntiles = chRows / RT;

  const float sgm = (float)(*sigma_p);
  const float k2 = LOG2E / (2.f * sgm * sgm);  // log2(e)/(2 sigma^2)
  const float c1 = 2.f * k2;

  // ---- B panel -> registers, staged in two 32 KB halves through S ----
  short8_t bfr[2][8];
#pragma unroll
  for (int H = 0; H < 2; ++H) {
#pragma unroll
    for (int i = 0; i < 4; ++i) {
      int o = i * 8192 + tid * 16;
      int h = o >> 14, r = (o >> 7) & 127, sg = ((o >> 4) & 7) ^ (r & 7);
      GLOAD_LDS16(Bbf + (size_t)(col0 + r) * Z + H * 128 + h * 64 + sg * 8, Sb + o);
    }
    __syncthreads();
#pragma unroll
    for (int c = 0; c < 2; ++c) {
      int rb = wc * 32 + c * 16 + laneLo;
#pragma unroll
      for (int kk = 0; kk < 4; ++kk) {
        int h = kk >> 1;
        int cb = (kk & 1) * 64 + laneHi * 16;
        bfr[c][H * 4 + kk] = *reinterpret_cast<const short8_t*>(
            Sb + h * 16384 + rb * 128 + (cb ^ ((rb & 7) << 4)));
      }
    }
    __syncthreads();
  }
  float bL[2];
#pragma unroll
  for (int c = 0; c < 2; ++c)
    bL[c] = b2[col0 + wc * 32 + c * 16 + laneLo] * k2;

  f32x4 acc[2][2];
#pragma unroll
  for (int a = 0; a < 2; ++a)
#pragma unroll
    for (int c = 0; c < 2; ++c) acc[a][c] = f32x4{0.f, 0.f, 0.f, 0.f};
  float m_run[2] = {-1e30f, -1e30f};
  float s_run[2] = {0.f, 0.f};

  STAGE_A(0, 0, 0);
  STAGE_A(1, 0, 1);
  __syncthreads();

  for (int t = 0; t < ntiles; ++t) {
    COMPUTE(0, 0);
    __syncthreads();  // buf0 free; drains prev iter's buf1 stage
    if (t + 1 < ntiles) STAGE_A(0, t + 1, 0);

    // a2 prefetch for epilogue (L2-hit; hides under COMPUTE(1))
    const int rowt = row0base + t * RT + wr * 32;
    const float4 av0 = *reinterpret_cast<const float4*>(a2 + rowt + laneHi * 4);
    const float4 av1 = *reinterpret_cast<const float4*>(a2 + rowt + 16 + laneHi * 4);

    COMPUTE(1, 1);

    // ---- epilogue: 16 logits/lane, online (max, sumexp) per column, base 2 ----
    float aL[2][4];
    aL[0][0] = av0.x * k2; aL[0][1] = av0.y * k2;
    aL[0][2] = av0.z * k2; aL[0][3] = av0.w * k2;
    aL[1][0] = av1.x * k2; aL[1][1] = av1.y * k2;
    aL[1][2] = av1.z * k2; aL[1][3] = av1.w * k2;
#pragma unroll
    for (int c = 0; c < 2; ++c) {
      float v[8];
#pragma unroll
      for (int a = 0; a < 2; ++a)
#pragma unroll
        for (int j = 0; j < 4; ++j)
          v[a * 4 + j] = c1 * acc[a][c][j] - (aL[a][j] + bL[c]);
      float mx = fmaxf(fmaxf(fmaxf(v[0], v[1]), fmaxf(v[2], v[3])),
                       fmaxf(fmaxf(v[4], v[5]), fmaxf(v[6], v[7])));
      float nm = fmaxf(m_run[c], mx);
      float ssum = fast_exp2(v[0] - nm);
#pragma unroll
      for (int i = 1; i < 8; ++i) ssum += fast_exp2(v[i] - nm);
      s_run[c] = s_run[c] * fast_exp2(m_run[c] - nm) + ssum;
      m_run[c] = nm;
      acc[0][c] = f32x4{0.f, 0.f, 0.f, 0.f};
      acc[1][c] = f32x4{0.f, 0.f, 0.f, 0.f};
    }
    __syncthreads();  // buf1 free; drains this iter's buf0 stage
    if (t + 1 < ntiles) STAGE_A(1, t + 1, 1);
  }

  // ---- merge laneHi groups (shfl), then the two row-half waves (LDS) ----
#pragma unroll
  for (int c = 0; c < 2; ++c) {
#pragma unroll
    for (int off = 16; off <= 32; off <<= 1) {
      float om = __shfl_xor(m_run[c], off);
      float os = __shfl_xor(s_run[c], off);
      float nm = fmaxf(m_run[c], om);
      s_run[c] = s_run[c] * fast_exp2(m_run[c] - nm) + os * fast_exp2(om - nm);
      m_run[c] = nm;
    }
    if (laneHi == 0) {
      redM[wr][wc * 32 + c * 16 + laneLo] = m_run[c];
      redS[wr][wc * 32 + c * 16 + laneLo] = s_run[c];
    }
  }
  __syncthreads();
  if (tid < CG) {
    float m0 = redM[0][tid], m1 = redM[1][tid];
    float s0 = redS[0][tid], s1 = redS[1][tid];
    float Mx = fmaxf(m0, m1);
    float Sx = s0 * fast_exp2(m0 - Mx) + s1 * fast_exp2(m1 - Mx);
    part[(size_t)y * Mtot + col0 + tid] = make_float2(Mx, Sx);
  }
}

// Merge NCH partials per column -> lse (nat log); block-reduce; atomicAdd(-lse/M).
__global__ __launch_bounds__(256) void lse_finish(const float2* __restrict__ part,
                                                  int NB, int Mtot,
                                                  float* __restrict__ out) {
  int m = blockIdx.x * blockDim.x + threadIdx.x;
  float mx = -1e30f, s = 0.f;
  for (int b = 0; b < NB; ++b) {
    float2 p = part[(size_t)b * Mtot + m];
    float nm = fmaxf(mx, p.x);
    s = s * fast_exp2(mx - nm) + p.y * fast_exp2(p.x - nm);
    mx = nm;
  }
  float lse = LN2 * (mx + __log2f(s));
  float v = lse;
#pragma unroll
  for (int off = 32; off >= 1; off >>= 1) v += __shfl_xor(v, off);
  __shared__ float red[4];
  if ((threadIdx.x & 63) == 0) red[threadIdx.x >> 6] = v;
  __syncthreads();
  if (threadIdx.x == 0)
    atomicAdd(out, -(red[0] + red[1] + red[2] + red[3]) / (float)Mtot);
}

extern "C" void kernel_launch(void* const* d_in, const int* in_sizes, int n_in,
                              void* d_out, int out_size, void* d_ws, size_t ws_size,
                              hipStream_t stream) {
  const float* mean = (const float*)d_in[0];
  const float* e    = (const float*)d_in[1];
  const int* sigma  = (const int*)d_in[2];
  const int N_ = in_sizes[0] / Z;  // 32768
  const int M_ = in_sizes[1] / Z;  // 8192
  const int chRows = N_ / NCH;     // 4096

  char* ws = (char*)d_ws;
  unsigned short* Abf = (unsigned short*)ws; ws += (size_t)N_ * Z * sizeof(unsigned short);
  unsigned short* Bbf = (unsigned short*)ws; ws += (size_t)M_ * Z * sizeof(unsigned short);
  float* a2 = (float*)ws;                    ws += (size_t)N_ * sizeof(float);
  float* b2 = (float*)ws;                    ws += (size_t)M_ * sizeof(float);
  float2* part = (float2*)ws;                // NCH * M_ float2 = 512 KB

  hipMemsetAsync(d_out, 0, sizeof(float), stream);
  prep_kernel<<<1280, 256, 0, stream>>>(mean, e, Abf, a2, N_, M_);
  gemm_lse_kernel<<<(M_ / CG) * NCH, 512, 0, stream>>>(Abf, Bbf, a2, b2, sigma,
                                                       part, M_, chRows);
  lse_finish<<<M_ / 256, 256, 0, stream>>>(part, NCH, M_, (float*)d_out);
}